// Round 11
// baseline (729.883 us; speedup 1.0000x reference)
//
#include <hip/hip_runtime.h>
#include <hip/hip_fp16.h>

#define N_NODES 30000
#define N_EDGES 240000
#define EMB     300
#define NPAD    30080   // 235 * 128
#define K1      320     // padded EMB (gemm1 K, agg cols, fp16)
#define NP1     640     // padded 2*EMB (gemm1 out cols = gemm2 K)
#define NP2     384     // gemm2 padded col count / h2 fp16 row stride
#define HSH     304     // h row stride in fp16 elements
#define LAYERS  5

typedef _Float16 half8 __attribute__((ext_vector_type(8)));
typedef __attribute__((ext_vector_type(4))) float floatx4;
typedef float v2f __attribute__((ext_vector_type(2)));

// async 16B global->LDS (per-lane gptr, LDS dest = wave-uniform base + lane*16)
__device__ __forceinline__ void gload16(const void* g, void* l) {
  __builtin_amdgcn_global_load_lds(
      (const __attribute__((address_space(1))) unsigned int*)g,
      (__attribute__((address_space(3))) unsigned int*)l, 16, 0, 0);
}

__device__ __forceinline__ v2f h2f(__half2 h) {
  float2 f = __half22float2(h);
  v2f r; r.x = f.x; r.y = f.y; return r;
}

// ---------------- fused prep: zero deg/stat, convert weights, embed ----------------
__global__ __launch_bounds__(256)
void prep_kernel(const float* __restrict__ W1, const float* __restrict__ W2,
                 const float* __restrict__ b1, const float* __restrict__ b2,
                 const int* __restrict__ x, const float* __restrict__ emb1,
                 const float* __restrict__ emb2,
                 __half* __restrict__ w1t, __half* __restrict__ w2t,
                 float* __restrict__ b1p, float* __restrict__ b2p,
                 __half* __restrict__ h, int* __restrict__ deg,
                 float* __restrict__ stat) {
  const int Z0 = N_NODES;                       // deg zero
  const int Z1 = Z0 + LAYERS * 2 * EMB;         // stat zero
  const int R0 = Z1 + LAYERS * NP1 * K1;        // w1t
  const int R1 = R0 + LAYERS * NP2 * NP1;       // w2t
  const int R2 = R1 + LAYERS * NP1;             // b1p
  const int R3 = R2 + LAYERS * NP2;             // b2p
  const int R4 = R3 + N_NODES * HSH;            // embed
  for (int i = blockIdx.x * 256 + threadIdx.x; i < R4; i += gridDim.x * 256) {
    if (i < Z0) {
      deg[i] = 0;
    } else if (i < Z1) {
      stat[i - Z0] = 0.f;
    } else if (i < R0) {
      int idx = i - Z1;
      int l = idx / (NP1 * K1);
      int rem = idx % (NP1 * K1);
      int n = rem / K1, k = rem % K1;
      float v = (n < 2 * EMB && k < EMB)
                    ? W1[(size_t)l * EMB * 2 * EMB + (size_t)k * 2 * EMB + n] : 0.f;
      w1t[idx] = __float2half(v);
    } else if (i < R1) {
      int idx = i - R0;
      int l = idx / (NP2 * NP1);
      int rem = idx % (NP2 * NP1);
      int n = rem / NP1, k = rem % NP1;
      float v = (n < EMB && k < 2 * EMB)
                    ? W2[(size_t)l * 2 * EMB * EMB + (size_t)k * EMB + n] : 0.f;
      w2t[idx] = __float2half(v);
    } else if (i < R2) {
      int idx = i - R1;
      int l = idx / NP1, j = idx % NP1;
      b1p[idx] = (j < 2 * EMB) ? b1[l * 2 * EMB + j] : 0.f;
    } else if (i < R3) {
      int idx = i - R2;
      int l = idx / NP2, j = idx % NP2;
      b2p[idx] = (j < EMB) ? b2[l * EMB + j] : 0.f;
    } else {
      int j = i - R3;
      int node = j / HSH, c = j - node * HSH;
      if (c < EMB) {
        int t0 = x[node * 2], t1 = x[node * 2 + 1];
        h[(size_t)node * HSH + c] = __float2half(emb1[t0 * EMB + c] + emb2[t1 * EMB + c]);
      }
    }
  }
}

// ---------------- CSR build ----------------
__global__ void count_kernel(const int* __restrict__ ei, int* __restrict__ deg) {
  int e = blockIdx.x * 256 + threadIdx.x;
  if (e < N_EDGES) atomicAdd(&deg[ei[N_EDGES + e]], 1);
}

#define SCH 30   // 1024 * 30 = 30720 >= N_NODES
__global__ __launch_bounds__(1024)
void scan_kernel(const int* __restrict__ deg, int* __restrict__ row_ptr,
                 int* __restrict__ curs) {
  int tid = threadIdx.x;
  int base = tid * SCH;
  int loc[SCH];
  int s = 0;
#pragma unroll
  for (int j = 0; j < SCH; ++j) {
    int i = base + j;
    int v = (i < N_NODES) ? deg[i] : 0;
    loc[j] = s;          // exclusive prefix within chunk
    s += v;
  }
  int lane = tid & 63, wv = tid >> 6;
  int x = s;
#pragma unroll
  for (int o = 1; o < 64; o <<= 1) {
    int y = __shfl_up(x, o, 64);
    if (lane >= o) x += y;
  }
  __shared__ int wsum[16], woff[16];
  if (lane == 63) wsum[wv] = x;
  __syncthreads();
  if (tid == 0) {
    int acc = 0;
    for (int w = 0; w < 16; ++w) { woff[w] = acc; acc += wsum[w]; }
    row_ptr[N_NODES] = acc;
  }
  __syncthreads();
  int excl = woff[wv] + x - s;    // exclusive prefix of this thread's chunk
#pragma unroll
  for (int j = 0; j < SCH; ++j) {
    int i = base + j;
    if (i < N_NODES) { int val = excl + loc[j]; row_ptr[i] = val; curs[i] = val; }
  }
}

__global__ void fill_kernel(const int* __restrict__ ei, const int* __restrict__ ea,
                            int* __restrict__ cursor, int* __restrict__ ebuf) {
  int e = blockIdx.x * 256 + threadIdx.x;
  if (e >= N_EDGES) return;
  int d = ei[N_EDGES + e];
  int pos = atomicAdd(&cursor[d], 1);
  ebuf[pos] = ei[e] * 32 + (ea[2 * e] * 3 + ea[2 * e + 1]);  // src*32 + combo
}

// ---------------- aggregation: persistent blocks, fused BN+ReLU, 8-edge batch ----------------
// R11: main loop batches 8 edges (24 gathers issued before any accumulation).
// R10 counters (VALUBusy 43.9, HBM 26%, VGPR 36) showed latency-bound with
// only ~12 loads in flight; target VGPR <= 64 to keep full 32-wave occupancy.
template<int BN>
__global__ __launch_bounds__(256)
void aggregate_kernel(const __half* __restrict__ h,   // BN ? h2 : hbuf
                      const float* __restrict__ stats,  // prev layer (BN only)
                      const float* __restrict__ gamma,  // prev layer (BN only)
                      const float* __restrict__ beta,   // prev layer (BN only)
                      const int* __restrict__ row_ptr,
                      const int* __restrict__ ebuf,
                      const float* __restrict__ e1,   // [6,300] this layer
                      const float* __restrict__ e2,   // [3,300] this layer
                      __half* __restrict__ agg) {
  const int STR = BN ? NP2 : HSH;   // fp16 row stride of gather source
  __shared__ __half2 combo[18][150];   // 10.8 KB
  int tid = threadIdx.x;
  for (int idx = tid; idx < 18 * 150; idx += 256) {
    int t = idx / 150, p = idx % 150;
    int a0 = t / 3, a1 = t % 3;
    combo[t][p] = __floats2half2_rn(e1[a0 * EMB + 2 * p]     + e2[a1 * EMB + 2 * p],
                                    e1[a0 * EMB + 2 * p + 1] + e2[a1 * EMB + 2 * p + 1]);
  }
  __syncthreads();
  int wave = tid >> 6, lane = tid & 63;
  int p2 = lane + 128;
  bool has2 = (p2 < 150);

  // per-thread BN scale/shift for the 3 owned half2 column pairs
  v2f sc[3], sh[3];
  if (BN) {
    const float invN = 1.0f / (float)N_NODES;
    int cols[3] = {2 * lane, 2 * (lane + 64), 2 * p2};
#pragma unroll
    for (int k = 0; k < 3; ++k) {
      if (k == 2 && !has2) { sc[2].x = sc[2].y = 1.f; sh[2].x = sh[2].y = 0.f; break; }
      int c = cols[k];
      float m0 = stats[c] * invN, m1 = stats[c + 1] * invN;
      float va = stats[EMB + c] * invN - m0 * m0;
      float vb = stats[EMB + c + 1] * invN - m1 * m1;
      sc[k].x = gamma[c] * rsqrtf(va + 1e-5f);      sh[k].x = beta[c] - m0 * sc[k].x;
      sc[k].y = gamma[c + 1] * rsqrtf(vb + 1e-5f);  sh[k].y = beta[c + 1] - m1 * sc[k].y;
    }
  }
  // gathered-value transform: BN ? relu(x*sc+sh) : x
  auto xf = [&](__half2 x, int k) -> v2f {
    v2f f = h2f(x);
    if (BN) {
      f = f * sc[k] + sh[k];
      f.x = fmaxf(f.x, 0.f); f.y = fmaxf(f.y, 0.f);
    }
    return f;
  };

  for (int node = blockIdx.x * 4 + wave; node < NPAD; node += gridDim.x * 4) {
    float a0x = 0.f, a0y = 0.f, a1x = 0.f, a1y = 0.f, a2x = 0.f, a2y = 0.f;
    float b0x = 0.f, b0y = 0.f, b1x = 0.f, b1y = 0.f, b2x = 0.f, b2y = 0.f;
    if (node < N_NODES) {
      int ebeg = row_ptr[node], eend = row_ptr[node + 1];
      int e = ebeg;
      // ---- 8-edge batch: issue ALL 24 gathers, then accumulate ----
      for (; e + 8 <= eend; e += 8) {
        int v[8];
#pragma unroll
        for (int j = 0; j < 8; ++j) v[j] = ebuf[e + j];
        const __half2* hp[8];
#pragma unroll
        for (int j = 0; j < 8; ++j) hp[j] = (const __half2*)(h + (size_t)(v[j] >> 5) * STR);
        __half2 x0[8], x1[8], x2[8];
#pragma unroll
        for (int j = 0; j < 8; ++j) { x0[j] = hp[j][lane]; x1[j] = hp[j][lane + 64]; }
        if (has2) {
#pragma unroll
          for (int j = 0; j < 8; ++j) x2[j] = hp[j][p2];
        }
#pragma unroll
        for (int j = 0; j < 8; ++j) {
          int tc = v[j] & 31;
          v2f g; float2 f;
          if (j & 1) {
            g = xf(x0[j], 0); b0x += g.x; b0y += g.y;
            f = __half22float2(combo[tc][lane]); b0x += f.x; b0y += f.y;
            g = xf(x1[j], 1); b1x += g.x; b1y += g.y;
            f = __half22float2(combo[tc][lane + 64]); b1x += f.x; b1y += f.y;
            if (has2) {
              g = xf(x2[j], 2); b2x += g.x; b2y += g.y;
              f = __half22float2(combo[tc][p2]); b2x += f.x; b2y += f.y;
            }
          } else {
            g = xf(x0[j], 0); a0x += g.x; a0y += g.y;
            f = __half22float2(combo[tc][lane]); a0x += f.x; a0y += f.y;
            g = xf(x1[j], 1); a1x += g.x; a1y += g.y;
            f = __half22float2(combo[tc][lane + 64]); a1x += f.x; a1y += f.y;
            if (has2) {
              g = xf(x2[j], 2); a2x += g.x; a2y += g.y;
              f = __half22float2(combo[tc][p2]); a2x += f.x; a2y += f.y;
            }
          }
        }
      }
      // ---- 2-edge pairs ----
      for (; e + 2 <= eend; e += 2) {
        int v0 = ebuf[e], v1 = ebuf[e + 1];
        int s0 = v0 >> 5, t0 = v0 & 31;
        int s1 = v1 >> 5, t1 = v1 & 31;
        const __half2* hp0 = (const __half2*)(h + (size_t)s0 * STR);
        const __half2* hp1 = (const __half2*)(h + (size_t)s1 * STR);
        v2f g; float2 f;
        g = xf(hp0[lane], 0);      a0x += g.x; a0y += g.y;
        f = __half22float2(combo[t0][lane]); a0x += f.x; a0y += f.y;
        g = xf(hp0[lane + 64], 1); a1x += g.x; a1y += g.y;
        f = __half22float2(combo[t0][lane + 64]); a1x += f.x; a1y += f.y;
        g = xf(hp1[lane], 0);      b0x += g.x; b0y += g.y;
        f = __half22float2(combo[t1][lane]); b0x += f.x; b0y += f.y;
        g = xf(hp1[lane + 64], 1); b1x += g.x; b1y += g.y;
        f = __half22float2(combo[t1][lane + 64]); b1x += f.x; b1y += f.y;
        if (has2) {
          g = xf(hp0[p2], 2); a2x += g.x; a2y += g.y;
          f = __half22float2(combo[t0][p2]); a2x += f.x; a2y += f.y;
          g = xf(hp1[p2], 2); b2x += g.x; b2y += g.y;
          f = __half22float2(combo[t1][p2]); b2x += f.x; b2y += f.y;
        }
      }
      // ---- tail edge (if odd count) + self loop ----
      for (; e <= eend; ++e) {
        int s, t;
        if (e < eend) { int v = ebuf[e]; s = v >> 5; t = v & 31; }
        else          { s = node;        t = 4 * 3 + 0; }
        const __half2* hp = (const __half2*)(h + (size_t)s * STR);
        v2f g; float2 f;
        g = xf(hp[lane], 0);      a0x += g.x; a0y += g.y;
        f = __half22float2(combo[t][lane]); a0x += f.x; a0y += f.y;
        g = xf(hp[lane + 64], 1); a1x += g.x; a1y += g.y;
        f = __half22float2(combo[t][lane + 64]); a1x += f.x; a1y += f.y;
        if (has2) {
          g = xf(hp[p2], 2); a2x += g.x; a2y += g.y;
          f = __half22float2(combo[t][p2]); a2x += f.x; a2y += f.y;
        }
      }
    }
    a0x += b0x; a0y += b0y; a1x += b1x; a1y += b1y; a2x += b2x; a2y += b2y;
    __half2* op = (__half2*)(agg + (size_t)node * K1);
    op[lane]      = __floats2half2_rn(a0x, a0y);
    op[lane + 64] = __floats2half2_rn(a1x, a1y);
    if (p2 < 160) op[p2] = has2 ? __floats2half2_rn(a2x, a2y)
                                : __floats2half2_rn(0.f, 0.f);   // zero K-pad cols
  }
}

// ---------------- fp16 MFMA GEMM: C = act(A @ B^T + bias) ----------------
// R11: launch_bounds 3 -> 4 blocks/CU. The per-K-step __syncthreads vmcnt
// drain (~500-600cyc L3 latency) is hidden only by OTHER resident blocks
// (R4 direct measurement: 75% stall at 3 blocks/CU). VGPR budget at 4/CU is
// 128: acc 64 + frags 16 + addr ~24 fits. LDS 32KB x 4 = 128 <= 160.
template<int RELU, int STATS>
__global__ __launch_bounds__(256, 4)
void gemm_kernel(const __half* __restrict__ A, int lda,
                 const __half* __restrict__ Bt, int ldb,
                 const float* __restrict__ bias,
                 __half* __restrict__ C, int ldc, int K,
                 float* __restrict__ stats) {
  __shared__ _Float16 As[2][128 * 32];   // double-buffered, 32 KB A+B
  __shared__ _Float16 Bs[2][128 * 32];
  __shared__ float cs[128], cq[128];
  int tid = threadIdx.x;
  int wave = tid >> 6, lane = tid & 63;
  int wm = wave >> 1, wn = wave & 1;
  int row0 = blockIdx.y * 128, col0 = blockIdx.x * 128;   // x = column tile (fast)
  int sr = tid >> 2, sc = (tid & 3) * 8;           // staging row / fp16 col chunk
  const __half* ga0 = A + (size_t)(row0 + sr) * lda + sc;
  const __half* ga1 = A + (size_t)(row0 + 64 + sr) * lda + sc;
  const __half* gb0 = Bt + (size_t)(col0 + sr) * ldb + sc;
  const __half* gb1 = Bt + (size_t)(col0 + 64 + sr) * ldb + sc;
  int soff = sr * 32 + sc;                          // lane-linear: tid*16 bytes
  int aoff = (wm * 64 + (lane & 15)) * 32 + (lane >> 4) * 8;
  int boff = (wn * 64 + (lane & 15)) * 32 + (lane >> 4) * 8;

  if (STATS && tid < 128) { cs[tid] = 0.f; cq[tid] = 0.f; }

  floatx4 zero4 = {0.f, 0.f, 0.f, 0.f};
  floatx4 acc[4][4];
#pragma unroll
  for (int i = 0; i < 4; ++i)
#pragma unroll
    for (int j = 0; j < 4; ++j) acc[i][j] = zero4;

  // prologue: stage tile 0 into buffer 0
  gload16(ga0, &As[0][soff]);
  gload16(ga1, &As[0][soff + 2048]);
  gload16(gb0, &Bs[0][soff]);
  gload16(gb1, &Bs[0][soff + 2048]);
  __syncthreads();   // vmcnt(0) drain + barrier: tile 0 resident

  int nT = K >> 5;
  int cur = 0;
  for (int t = 0; t < nT; ++t) {
    if (t + 1 < nT) {            // issue next-tile loads BEFORE compute
      int kc = (t + 1) << 5;
      int nb = cur ^ 1;
      gload16(ga0 + kc, &As[nb][soff]);
      gload16(ga1 + kc, &As[nb][soff + 2048]);
      gload16(gb0 + kc, &Bs[nb][soff]);
      gload16(gb1 + kc, &Bs[nb][soff + 2048]);
    }
    half8 af[4], bfr[4];
#pragma unroll
    for (int mi = 0; mi < 4; ++mi)
      af[mi] = *(const half8*)&As[cur][aoff + mi * 512];
#pragma unroll
    for (int ni = 0; ni < 4; ++ni)
      bfr[ni] = *(const half8*)&Bs[cur][boff + ni * 512];
#pragma unroll
    for (int mi = 0; mi < 4; ++mi)
#pragma unroll
      for (int ni = 0; ni < 4; ++ni)
        acc[mi][ni] = __builtin_amdgcn_mfma_f32_16x16x32_f16(af[mi], bfr[ni], acc[mi][ni], 0, 0, 0);
    __syncthreads();   // one barrier/K-step: next tile ready + reads of cur done
    cur ^= 1;
  }

  // epilogue: C/D layout col=lane&15, row=quad*4+reg
  float ls[4] = {0.f, 0.f, 0.f, 0.f}, lq[4] = {0.f, 0.f, 0.f, 0.f};
#pragma unroll
  for (int mi = 0; mi < 4; ++mi) {
#pragma unroll
    for (int ni = 0; ni < 4; ++ni) {
      int col = col0 + wn * 64 + ni * 16 + (lane & 15);
      float bv = bias[col];
#pragma unroll
      for (int r = 0; r < 4; ++r) {
        int row = row0 + wm * 64 + mi * 16 + (lane >> 4) * 4 + r;
        float v = acc[mi][ni][r] + bv;
        if (RELU) v = fmaxf(v, 0.f);
        C[(size_t)row * ldc + col] = __float2half(v);
        if (STATS && row < N_NODES) { ls[ni] += v; lq[ni] += v * v; }
      }
    }
  }
  if (STATS) {
#pragma unroll
    for (int ni = 0; ni < 4; ++ni) {
      int ci = wn * 64 + ni * 16 + (lane & 15);
      atomicAdd(&cs[ci], ls[ni]);
      atomicAdd(&cq[ci], lq[ni]);
    }
    __syncthreads();
    int col = col0 + tid;
    if (tid < 128 && col < EMB) {
      atomicAdd(&stats[col], cs[tid]);
      atomicAdd(&stats[EMB + col], cq[tid]);
    }
  }
}

// ---------------- batchnorm apply, final layer only: h2 -> fp32 out ----------------
__global__ __launch_bounds__(256)
void bn_kernel(const __half* __restrict__ h2, const float* __restrict__ stats,
               const float* __restrict__ gamma, const float* __restrict__ beta,
               float* __restrict__ fout) {
  const float invN = 1.0f / (float)N_NODES;
  const int total = N_NODES * 150;
  for (int i = blockIdx.x * 256 + threadIdx.x; i < total; i += gridDim.x * 256) {
    int node = i / 150;
    int c = (i - node * 150) * 2;
    float m0 = stats[c] * invN,      m1 = stats[c + 1] * invN;
    float v0 = stats[EMB + c] * invN - m0 * m0;
    float v1 = stats[EMB + c + 1] * invN - m1 * m1;
    float s0 = gamma[c] * rsqrtf(v0 + 1e-5f);
    float s1 = gamma[c + 1] * rsqrtf(v1 + 1e-5f);
    float t0 = beta[c] - m0 * s0, t1 = beta[c + 1] - m1 * s1;
    float2 u = __half22float2(*(const __half2*)&h2[(size_t)node * NP2 + c]);
    fout[(size_t)node * EMB + c]     = u.x * s0 + t0;
    fout[(size_t)node * EMB + c + 1] = u.y * s1 + t1;
  }
}

extern "C" void kernel_launch(void* const* d_in, const int* in_sizes, int n_in,
                              void* d_out, int out_size, void* d_ws, size_t ws_size,
                              hipStream_t stream) {
  const int*   x      = (const int*)d_in[0];
  const int*   ei     = (const int*)d_in[1];
  const int*   ea     = (const int*)d_in[2];
  const float* x_emb1 = (const float*)d_in[3];
  const float* x_emb2 = (const float*)d_in[4];
  const float* edge1  = (const float*)d_in[5];
  const float* edge2  = (const float*)d_in[6];
  const float* W1     = (const float*)d_in[7];
  const float* b1     = (const float*)d_in[8];
  const float* W2     = (const float*)d_in[9];
  const float* b2     = (const float*)d_in[10];
  const float* gamma  = (const float*)d_in[11];
  const float* beta   = (const float*)d_in[12];
  float* out = (float*)d_out;

  char* ws = (char*)d_ws;
  size_t off = 0;
  auto nxt = [&](size_t bytes) {
    void* p = ws + off;
    off += (bytes + 255) & ~(size_t)255;
    return p;
  };
  // Aliasing: h2 is READ by the next layer's aggregate (while aggb is
  // written), so h2 must NOT alias aggb. Timeline-checked layout:
  //   region R: hbuf (read only by layer-0 aggregate) aliases tbuf (first
  //             written at layer-0 gemm1, after hbuf's last read).
  //   aggb, h2: separate.
  size_t tbuf_bytes = (size_t)NPAD * NP1 * 2;        // 38.5 MB
  size_t hbuf_bytes = (size_t)N_NODES * HSH * 2;     // 18.2 MB
  char* R = (char*)nxt(tbuf_bytes > hbuf_bytes ? tbuf_bytes : hbuf_bytes);
  __half* hbuf = (__half*)R;
  __half* tbuf = (__half*)R;
  __half* aggb = (__half*)nxt((size_t)NPAD * K1 * 2);   // 19.3 MB
  __half* h2   = (__half*)nxt((size_t)NPAD * NP2 * 2);  // 23.1 MB
  __half* w1t  = (__half*)nxt((size_t)LAYERS * NP1 * K1 * 2);
  __half* w2t  = (__half*)nxt((size_t)LAYERS * NP2 * NP1 * 2);
  float*  b1p  = (float*)nxt((size_t)LAYERS * NP1 * 4);
  float*  b2p  = (float*)nxt((size_t)LAYERS * NP2 * 4);
  float*  stat = (float*)nxt((size_t)LAYERS * 2 * EMB * 4);
  int*    deg  = (int*)nxt((size_t)N_NODES * 4);
  int*    rptr = (int*)nxt((size_t)(N_NODES + 1) * 4);
  int*    curs = (int*)nxt((size_t)N_NODES * 4);
  int*    ebuf = (int*)nxt((size_t)N_EDGES * 4);
  // total ~92 MB

  prep_kernel<<<2048, 256, 0, stream>>>(W1, W2, b1, b2, x, x_emb1, x_emb2,
                                        w1t, w2t, b1p, b2p, hbuf, deg, stat);

  count_kernel<<<(N_EDGES + 255) / 256, 256, 0, stream>>>(ei, deg);
  scan_kernel<<<1, 1024, 0, stream>>>(deg, rptr, curs);
  fill_kernel<<<(N_EDGES + 255) / 256, 256, 0, stream>>>(ei, ea, curs, ebuf);

  for (int l = 0; l < LAYERS; ++l) {
    if (l == 0) {
      aggregate_kernel<0><<<2048, 256, 0, stream>>>(
          hbuf, nullptr, nullptr, nullptr, rptr, ebuf,
          edge1 + (size_t)l * 6 * EMB, edge2 + (size_t)l * 3 * EMB, aggb);
    } else {
      aggregate_kernel<1><<<2048, 256, 0, stream>>>(
          h2, stat + (size_t)(l - 1) * 2 * EMB,
          gamma + (size_t)(l - 1) * EMB, beta + (size_t)(l - 1) * EMB,
          rptr, ebuf,
          edge1 + (size_t)l * 6 * EMB, edge2 + (size_t)l * 3 * EMB, aggb);
    }
    gemm_kernel<1, 0><<<dim3(NP1 / 128, NPAD / 128), 256, 0, stream>>>(
        aggb, K1, w1t + (size_t)l * NP1 * K1, K1, b1p + l * NP1, tbuf, NP1, K1, nullptr);
    gemm_kernel<0, 1><<<dim3(NP2 / 128, NPAD / 128), 256, 0, stream>>>(
        tbuf, NP1, w2t + (size_t)l * NP2 * NP1, NP1, b2p + l * NP2, h2, NP2, NP1,
        stat + l * 2 * EMB);
  }
  bn_kernel<<<1024, 256, 0, stream>>>(
      h2, stat + (size_t)(LAYERS - 1) * 2 * EMB,
      gamma + (size_t)(LAYERS - 1) * EMB, beta + (size_t)(LAYERS - 1) * EMB, out);
}

// Round 14
// 718.074 us; speedup vs baseline: 1.0164x; 1.0164x over previous
//
#include <hip/hip_runtime.h>
#include <hip/hip_fp16.h>

#define N_NODES 30000
#define N_EDGES 240000
#define EMB     300
#define NPAD    30080   // 235 * 128
#define K1      320     // padded EMB (gemm1 K, agg cols, fp16)
#define NP1     640     // padded 2*EMB (gemm1 out cols = gemm2 K)
#define NP2     384     // gemm2 padded col count / h2 fp16 row stride
#define HSH     304     // h row stride in fp16 elements
#define LAYERS  5

typedef _Float16 half8 __attribute__((ext_vector_type(8)));
typedef __attribute__((ext_vector_type(4))) float floatx4;
typedef float v2f __attribute__((ext_vector_type(2)));

// async 16B global->LDS (per-lane gptr, LDS dest = wave-uniform base + lane*16)
__device__ __forceinline__ void gload16(const void* g, void* l) {
  __builtin_amdgcn_global_load_lds(
      (const __attribute__((address_space(1))) unsigned int*)g,
      (__attribute__((address_space(3))) unsigned int*)l, 16, 0, 0);
}

__device__ __forceinline__ v2f h2f(__half2 h) {
  float2 f = __half22float2(h);
  v2f r; r.x = f.x; r.y = f.y; return r;
}

// ---------------- fused prep: zero deg/stat, convert weights, embed ----------------
__global__ __launch_bounds__(256)
void prep_kernel(const float* __restrict__ W1, const float* __restrict__ W2,
                 const float* __restrict__ b1, const float* __restrict__ b2,
                 const int* __restrict__ x, const float* __restrict__ emb1,
                 const float* __restrict__ emb2,
                 __half* __restrict__ w1t, __half* __restrict__ w2t,
                 float* __restrict__ b1p, float* __restrict__ b2p,
                 __half* __restrict__ h, int* __restrict__ deg,
                 float* __restrict__ stat) {
  const int Z0 = N_NODES;                       // deg zero
  const int Z1 = Z0 + LAYERS * 2 * EMB;         // stat zero
  const int R0 = Z1 + LAYERS * NP1 * K1;        // w1t
  const int R1 = R0 + LAYERS * NP2 * NP1;       // w2t
  const int R2 = R1 + LAYERS * NP1;             // b1p
  const int R3 = R2 + LAYERS * NP2;             // b2p
  const int R4 = R3 + N_NODES * HSH;            // embed
  for (int i = blockIdx.x * 256 + threadIdx.x; i < R4; i += gridDim.x * 256) {
    if (i < Z0) {
      deg[i] = 0;
    } else if (i < Z1) {
      stat[i - Z0] = 0.f;
    } else if (i < R0) {
      int idx = i - Z1;
      int l = idx / (NP1 * K1);
      int rem = idx % (NP1 * K1);
      int n = rem / K1, k = rem % K1;
      float v = (n < 2 * EMB && k < EMB)
                    ? W1[(size_t)l * EMB * 2 * EMB + (size_t)k * 2 * EMB + n] : 0.f;
      w1t[idx] = __float2half(v);
    } else if (i < R1) {
      int idx = i - R0;
      int l = idx / (NP2 * NP1);
      int rem = idx % (NP2 * NP1);
      int n = rem / NP1, k = rem % NP1;
      float v = (n < EMB && k < 2 * EMB)
                    ? W2[(size_t)l * 2 * EMB * EMB + (size_t)k * EMB + n] : 0.f;
      w2t[idx] = __float2half(v);
    } else if (i < R2) {
      int idx = i - R1;
      int l = idx / NP1, j = idx % NP1;
      b1p[idx] = (j < 2 * EMB) ? b1[l * 2 * EMB + j] : 0.f;
    } else if (i < R3) {
      int idx = i - R2;
      int l = idx / NP2, j = idx % NP2;
      b2p[idx] = (j < EMB) ? b2[l * EMB + j] : 0.f;
    } else {
      int j = i - R3;
      int node = j / HSH, c = j - node * HSH;
      if (c < EMB) {
        int t0 = x[node * 2], t1 = x[node * 2 + 1];
        h[(size_t)node * HSH + c] = __float2half(emb1[t0 * EMB + c] + emb2[t1 * EMB + c]);
      }
    }
  }
}

// ---------------- CSR build ----------------
__global__ void count_kernel(const int* __restrict__ ei, int* __restrict__ deg) {
  int e = blockIdx.x * 256 + threadIdx.x;
  if (e < N_EDGES) atomicAdd(&deg[ei[N_EDGES + e]], 1);
}

#define SCH 30   // 1024 * 30 = 30720 >= N_NODES
__global__ __launch_bounds__(1024)
void scan_kernel(const int* __restrict__ deg, int* __restrict__ row_ptr,
                 int* __restrict__ curs) {
  int tid = threadIdx.x;
  int base = tid * SCH;
  int loc[SCH];
  int s = 0;
#pragma unroll
  for (int j = 0; j < SCH; ++j) {
    int i = base + j;
    int v = (i < N_NODES) ? deg[i] : 0;
    loc[j] = s;          // exclusive prefix within chunk
    s += v;
  }
  int lane = tid & 63, wv = tid >> 6;
  int x = s;
#pragma unroll
  for (int o = 1; o < 64; o <<= 1) {
    int y = __shfl_up(x, o, 64);
    if (lane >= o) x += y;
  }
  __shared__ int wsum[16], woff[16];
  if (lane == 63) wsum[wv] = x;
  __syncthreads();
  if (tid == 0) {
    int acc = 0;
    for (int w = 0; w < 16; ++w) { woff[w] = acc; acc += wsum[w]; }
    row_ptr[N_NODES] = acc;
  }
  __syncthreads();
  int excl = woff[wv] + x - s;    // exclusive prefix of this thread's chunk
#pragma unroll
  for (int j = 0; j < SCH; ++j) {
    int i = base + j;
    if (i < N_NODES) { int val = excl + loc[j]; row_ptr[i] = val; curs[i] = val; }
  }
}

__global__ void fill_kernel(const int* __restrict__ ei, const int* __restrict__ ea,
                            int* __restrict__ cursor, int* __restrict__ ebuf) {
  int e = blockIdx.x * 256 + threadIdx.x;
  if (e >= N_EDGES) return;
  int d = ei[N_EDGES + e];
  int pos = atomicAdd(&cursor[d], 1);
  ebuf[pos] = ei[e] * 32 + (ea[2 * e] * 3 + ea[2 * e + 1]);  // src*32 + combo
}

// ---------------- aggregation: persistent blocks, fused BN+ReLU, 4-edge batch ----------------
// R10-EXACT body (measured 45.2us, VGPR 36, passed R10). Do not modify.
template<int BN>
__global__ __launch_bounds__(256)
void aggregate_kernel(const __half* __restrict__ h,   // BN ? h2 : hbuf
                      const float* __restrict__ stats,  // prev layer (BN only)
                      const float* __restrict__ gamma,  // prev layer (BN only)
                      const float* __restrict__ beta,   // prev layer (BN only)
                      const int* __restrict__ row_ptr,
                      const int* __restrict__ ebuf,
                      const float* __restrict__ e1,   // [6,300] this layer
                      const float* __restrict__ e2,   // [3,300] this layer
                      __half* __restrict__ agg) {
  const int STR = BN ? NP2 : HSH;   // fp16 row stride of gather source
  __shared__ __half2 combo[18][150];   // 10.8 KB
  int tid = threadIdx.x;
  for (int idx = tid; idx < 18 * 150; idx += 256) {
    int t = idx / 150, p = idx % 150;
    int a0 = t / 3, a1 = t % 3;
    combo[t][p] = __floats2half2_rn(e1[a0 * EMB + 2 * p]     + e2[a1 * EMB + 2 * p],
                                    e1[a0 * EMB + 2 * p + 1] + e2[a1 * EMB + 2 * p + 1]);
  }
  __syncthreads();
  int wave = tid >> 6, lane = tid & 63;
  int p2 = lane + 128;
  bool has2 = (p2 < 150);

  // per-thread BN scale/shift for the 3 owned half2 column pairs
  v2f sc[3], sh[3];
  if (BN) {
    const float invN = 1.0f / (float)N_NODES;
    int cols[3] = {2 * lane, 2 * (lane + 64), 2 * p2};
#pragma unroll
    for (int k = 0; k < 3; ++k) {
      if (k == 2 && !has2) { sc[2].x = sc[2].y = 1.f; sh[2].x = sh[2].y = 0.f; break; }
      int c = cols[k];
      float m0 = stats[c] * invN, m1 = stats[c + 1] * invN;
      float va = stats[EMB + c] * invN - m0 * m0;
      float vb = stats[EMB + c + 1] * invN - m1 * m1;
      sc[k].x = gamma[c] * rsqrtf(va + 1e-5f);      sh[k].x = beta[c] - m0 * sc[k].x;
      sc[k].y = gamma[c + 1] * rsqrtf(vb + 1e-5f);  sh[k].y = beta[c + 1] - m1 * sc[k].y;
    }
  }
  // gathered-value transform: BN ? relu(x*sc+sh) : x
  auto xf = [&](__half2 x, int k) -> v2f {
    v2f f = h2f(x);
    if (BN) {
      f = f * sc[k] + sh[k];
      f.x = fmaxf(f.x, 0.f); f.y = fmaxf(f.y, 0.f);
    }
    return f;
  };

  for (int node = blockIdx.x * 4 + wave; node < NPAD; node += gridDim.x * 4) {
    float a0x = 0.f, a0y = 0.f, a1x = 0.f, a1y = 0.f, a2x = 0.f, a2y = 0.f;
    float b0x = 0.f, b0y = 0.f, b1x = 0.f, b1y = 0.f, b2x = 0.f, b2y = 0.f;
    if (node < N_NODES) {
      int ebeg = row_ptr[node], eend = row_ptr[node + 1];
      int e = ebeg;
      // ---- 4-edge unrolled main loop: batch all loads, then accumulate ----
      for (; e + 4 <= eend; e += 4) {
        int v0 = ebuf[e], v1 = ebuf[e + 1], v2 = ebuf[e + 2], v3 = ebuf[e + 3];
        const __half2* hp0 = (const __half2*)(h + (size_t)(v0 >> 5) * STR);
        const __half2* hp1 = (const __half2*)(h + (size_t)(v1 >> 5) * STR);
        const __half2* hp2 = (const __half2*)(h + (size_t)(v2 >> 5) * STR);
        const __half2* hp3 = (const __half2*)(h + (size_t)(v3 >> 5) * STR);
        int t0 = v0 & 31, t1 = v1 & 31, t2 = v2 & 31, t3 = v3 & 31;
        __half2 x00 = hp0[lane], x01 = hp0[lane + 64];
        __half2 x10 = hp1[lane], x11 = hp1[lane + 64];
        __half2 x20 = hp2[lane], x21 = hp2[lane + 64];
        __half2 x30 = hp3[lane], x31 = hp3[lane + 64];
        __half2 x02, x12, x22, x32;
        if (has2) { x02 = hp0[p2]; x12 = hp1[p2]; x22 = hp2[p2]; x32 = hp3[p2]; }
        __half2 c00 = combo[t0][lane], c01 = combo[t0][lane + 64];
        __half2 c10 = combo[t1][lane], c11 = combo[t1][lane + 64];
        __half2 c20 = combo[t2][lane], c21 = combo[t2][lane + 64];
        __half2 c30 = combo[t3][lane], c31 = combo[t3][lane + 64];
        v2f g; float2 f;
        g = xf(x00, 0); a0x += g.x; a0y += g.y;
        f = __half22float2(c00); a0x += f.x; a0y += f.y;
        g = xf(x01, 1); a1x += g.x; a1y += g.y;
        f = __half22float2(c01); a1x += f.x; a1y += f.y;
        g = xf(x10, 0); b0x += g.x; b0y += g.y;
        f = __half22float2(c10); b0x += f.x; b0y += f.y;
        g = xf(x11, 1); b1x += g.x; b1y += g.y;
        f = __half22float2(c11); b1x += f.x; b1y += f.y;
        g = xf(x20, 0); a0x += g.x; a0y += g.y;
        f = __half22float2(c20); a0x += f.x; a0y += f.y;
        g = xf(x21, 1); a1x += g.x; a1y += g.y;
        f = __half22float2(c21); a1x += f.x; a1y += f.y;
        g = xf(x30, 0); b0x += g.x; b0y += g.y;
        f = __half22float2(c30); b0x += f.x; b0y += f.y;
        g = xf(x31, 1); b1x += g.x; b1y += g.y;
        f = __half22float2(c31); b1x += f.x; b1y += f.y;
        if (has2) {
          g = xf(x02, 2); a2x += g.x; a2y += g.y;
          f = __half22float2(combo[t0][p2]); a2x += f.x; a2y += f.y;
          g = xf(x12, 2); b2x += g.x; b2y += g.y;
          f = __half22float2(combo[t1][p2]); b2x += f.x; b2y += f.y;
          g = xf(x22, 2); a2x += g.x; a2y += g.y;
          f = __half22float2(combo[t2][p2]); a2x += f.x; a2y += f.y;
          g = xf(x32, 2); b2x += g.x; b2y += g.y;
          f = __half22float2(combo[t3][p2]); b2x += f.x; b2y += f.y;
        }
      }
      // ---- 2-edge pairs ----
      for (; e + 2 <= eend; e += 2) {
        int v0 = ebuf[e], v1 = ebuf[e + 1];
        int s0 = v0 >> 5, t0 = v0 & 31;
        int s1 = v1 >> 5, t1 = v1 & 31;
        const __half2* hp0 = (const __half2*)(h + (size_t)s0 * STR);
        const __half2* hp1 = (const __half2*)(h + (size_t)s1 * STR);
        v2f g; float2 f;
        g = xf(hp0[lane], 0);      a0x += g.x; a0y += g.y;
        f = __half22float2(combo[t0][lane]); a0x += f.x; a0y += f.y;
        g = xf(hp0[lane + 64], 1); a1x += g.x; a1y += g.y;
        f = __half22float2(combo[t0][lane + 64]); a1x += f.x; a1y += f.y;
        g = xf(hp1[lane], 0);      b0x += g.x; b0y += g.y;
        f = __half22float2(combo[t1][lane]); b0x += f.x; b0y += f.y;
        g = xf(hp1[lane + 64], 1); b1x += g.x; b1y += g.y;
        f = __half22float2(combo[t1][lane + 64]); b1x += f.x; b1y += f.y;
        if (has2) {
          g = xf(hp0[p2], 2); a2x += g.x; a2y += g.y;
          f = __half22float2(combo[t0][p2]); a2x += f.x; a2y += f.y;
          g = xf(hp1[p2], 2); b2x += g.x; b2y += g.y;
          f = __half22float2(combo[t1][p2]); b2x += f.x; b2y += f.y;
        }
      }
      // ---- tail edge (if odd count) + self loop ----
      for (; e <= eend; ++e) {
        int s, t;
        if (e < eend) { int v = ebuf[e]; s = v >> 5; t = v & 31; }
        else          { s = node;        t = 4 * 3 + 0; }
        const __half2* hp = (const __half2*)(h + (size_t)s * STR);
        v2f g; float2 f;
        g = xf(hp[lane], 0);      a0x += g.x; a0y += g.y;
        f = __half22float2(combo[t][lane]); a0x += f.x; a0y += f.y;
        g = xf(hp[lane + 64], 1); a1x += g.x; a1y += g.y;
        f = __half22float2(combo[t][lane + 64]); a1x += f.x; a1y += f.y;
        if (has2) {
          g = xf(hp[p2], 2); a2x += g.x; a2y += g.y;
          f = __half22float2(combo[t][p2]); a2x += f.x; a2y += f.y;
        }
      }
    }
    a0x += b0x; a0y += b0y; a1x += b1x; a1y += b1y; a2x += b2x; a2y += b2y;
    __half2* op = (__half2*)(agg + (size_t)node * K1);
    op[lane]      = __floats2half2_rn(a0x, a0y);
    op[lane + 64] = __floats2half2_rn(a1x, a1y);
    if (p2 < 160) op[p2] = has2 ? __floats2half2_rn(a2x, a2y)
                                : __floats2half2_rn(0.f, 0.f);   // zero K-pad cols
  }
}

// ---------------- fp16 MFMA GEMM: C = act(A @ B^T + bias) ----------------
// R11-passed variant: plain-HIP dbuf + lb(256,4), 2D grid (x=col fastest).
// No XCD swizzle (R12/R13 source failed twice in the harness; swizzle is
// the one untested element and is dropped to de-risk).
template<int RELU, int STATS>
__global__ __launch_bounds__(256, 4)
void gemm_kernel(const __half* __restrict__ A, int lda,
                 const __half* __restrict__ Bt, int ldb,
                 const float* __restrict__ bias,
                 __half* __restrict__ C, int ldc, int K,
                 float* __restrict__ stats) {
  __shared__ _Float16 As[2][128 * 32];   // double-buffered, 32 KB A+B
  __shared__ _Float16 Bs[2][128 * 32];
  __shared__ float cs[128], cq[128];
  int tid = threadIdx.x;
  int wave = tid >> 6, lane = tid & 63;
  int wm = wave >> 1, wn = wave & 1;
  int row0 = blockIdx.y * 128, col0 = blockIdx.x * 128;   // x = column tile (fast)
  int sr = tid >> 2, sc = (tid & 3) * 8;           // staging row / fp16 col chunk
  const __half* ga0 = A + (size_t)(row0 + sr) * lda + sc;
  const __half* ga1 = A + (size_t)(row0 + 64 + sr) * lda + sc;
  const __half* gb0 = Bt + (size_t)(col0 + sr) * ldb + sc;
  const __half* gb1 = Bt + (size_t)(col0 + 64 + sr) * ldb + sc;
  int soff = sr * 32 + sc;                          // lane-linear: tid*16 bytes
  int aoff = (wm * 64 + (lane & 15)) * 32 + (lane >> 4) * 8;
  int boff = (wn * 64 + (lane & 15)) * 32 + (lane >> 4) * 8;

  if (STATS && tid < 128) { cs[tid] = 0.f; cq[tid] = 0.f; }

  floatx4 zero4 = {0.f, 0.f, 0.f, 0.f};
  floatx4 acc[4][4];
#pragma unroll
  for (int i = 0; i < 4; ++i)
#pragma unroll
    for (int j = 0; j < 4; ++j) acc[i][j] = zero4;

  // prologue: stage tile 0 into buffer 0
  gload16(ga0, &As[0][soff]);
  gload16(ga1, &As[0][soff + 2048]);
  gload16(gb0, &Bs[0][soff]);
  gload16(gb1, &Bs[0][soff + 2048]);
  __syncthreads();   // vmcnt(0) drain + barrier: tile 0 resident

  int nT = K >> 5;
  int cur = 0;
  for (int t = 0; t < nT; ++t) {
    if (t + 1 < nT) {            // issue next-tile loads BEFORE compute
      int kc = (t + 1) << 5;
      int nb = cur ^ 1;
      gload16(ga0 + kc, &As[nb][soff]);
      gload16(ga1 + kc, &As[nb][soff + 2048]);
      gload16(gb0 + kc, &Bs[nb][soff]);
      gload16(gb1 + kc, &Bs[nb][soff + 2048]);
    }
    half8 af[4], bfr[4];
#pragma unroll
    for (int mi = 0; mi < 4; ++mi)
      af[mi] = *(const half8*)&As[cur][aoff + mi * 512];
#pragma unroll
    for (int ni = 0; ni < 4; ++ni)
      bfr[ni] = *(const half8*)&Bs[cur][boff + ni * 512];
#pragma unroll
    for (int mi = 0; mi < 4; ++mi)
#pragma unroll
      for (int ni = 0; ni < 4; ++ni)
        acc[mi][ni] = __builtin_amdgcn_mfma_f32_16x16x32_f16(af[mi], bfr[ni], acc[mi][ni], 0, 0, 0);
    __syncthreads();   // one barrier/K-step: next tile ready + reads of cur done
    cur ^= 1;
  }

  // epilogue: C/D layout col=lane&15, row=quad*4+reg
  float ls[4] = {0.f, 0.f, 0.f, 0.f}, lq[4] = {0.f, 0.f, 0.f, 0.f};
#pragma unroll
  for (int mi = 0; mi < 4; ++mi) {
#pragma unroll
    for (int ni = 0; ni < 4; ++ni) {
      int col = col0 + wn * 64 + ni * 16 + (lane & 15);
      float bv = bias[col];
#pragma unroll
      for (int r = 0; r < 4; ++r) {
        int row = row0 + wm * 64 + mi * 16 + (lane >> 4) * 4 + r;
        float v = acc[mi][ni][r] + bv;
        if (RELU) v = fmaxf(v, 0.f);
        C[(size_t)row * ldc + col] = __float2half(v);
        if (STATS && row < N_NODES) { ls[ni] += v; lq[ni] += v * v; }
      }
    }
  }
  if (STATS) {
#pragma unroll
    for (int ni = 0; ni < 4; ++ni) {
      int ci = wn * 64 + ni * 16 + (lane & 15);
      atomicAdd(&cs[ci], ls[ni]);
      atomicAdd(&cq[ci], lq[ni]);
    }
    __syncthreads();
    int col = col0 + tid;
    if (tid < 128 && col < EMB) {
      atomicAdd(&stats[col], cs[tid]);
      atomicAdd(&stats[EMB + col], cq[tid]);
    }
  }
}

// ---------------- batchnorm apply, final layer only: h2 -> fp32 out ----------------
__global__ __launch_bounds__(256)
void bn_kernel(const __half* __restrict__ h2, const float* __restrict__ stats,
               const float* __restrict__ gamma, const float* __restrict__ beta,
               float* __restrict__ fout) {
  const float invN = 1.0f / (float)N_NODES;
  const int total = N_NODES * 150;
  for (int i = blockIdx.x * 256 + threadIdx.x; i < total; i += gridDim.x * 256) {
    int node = i / 150;
    int c = (i - node * 150) * 2;
    float m0 = stats[c] * invN,      m1 = stats[c + 1] * invN;
    float v0 = stats[EMB + c] * invN - m0 * m0;
    float v1 = stats[EMB + c + 1] * invN - m1 * m1;
    float s0 = gamma[c] * rsqrtf(v0 + 1e-5f);
    float s1 = gamma[c + 1] * rsqrtf(v1 + 1e-5f);
    float t0 = beta[c] - m0 * s0, t1 = beta[c + 1] - m1 * s1;
    float2 u = __half22float2(*(const __half2*)&h2[(size_t)node * NP2 + c]);
    fout[(size_t)node * EMB + c]     = u.x * s0 + t0;
    fout[(size_t)node * EMB + c + 1] = u.y * s1 + t1;
  }
}

extern "C" void kernel_launch(void* const* d_in, const int* in_sizes, int n_in,
                              void* d_out, int out_size, void* d_ws, size_t ws_size,
                              hipStream_t stream) {
  const int*   x      = (const int*)d_in[0];
  const int*   ei     = (const int*)d_in[1];
  const int*   ea     = (const int*)d_in[2];
  const float* x_emb1 = (const float*)d_in[3];
  const float* x_emb2 = (const float*)d_in[4];
  const float* edge1  = (const float*)d_in[5];
  const float* edge2  = (const float*)d_in[6];
  const float* W1     = (const float*)d_in[7];
  const float* b1     = (const float*)d_in[8];
  const float* W2     = (const float*)d_in[9];
  const float* b2     = (const float*)d_in[10];
  const float* gamma  = (const float*)d_in[11];
  const float* beta   = (const float*)d_in[12];
  float* out = (float*)d_out;

  char* ws = (char*)d_ws;
  size_t off = 0;
  auto nxt = [&](size_t bytes) {
    void* p = ws + off;
    off += (bytes + 255) & ~(size_t)255;
    return p;
  };
  // Aliasing: h2 is READ by the next layer's aggregate (while aggb is
  // written), so h2 must NOT alias aggb. Timeline-checked layout:
  //   region R: hbuf (read only by layer-0 aggregate) aliases tbuf (first
  //             written at layer-0 gemm1, after hbuf's last read).
  //   aggb, h2: separate.
  size_t tbuf_bytes = (size_t)NPAD * NP1 * 2;        // 38.5 MB
  size_t hbuf_bytes = (size_t)N_NODES * HSH * 2;     // 18.2 MB
  char* R = (char*)nxt(tbuf_bytes > hbuf_bytes ? tbuf_bytes : hbuf_bytes);
  __half* hbuf = (__half*)R;
  __half* tbuf = (__half*)R;
  __half* aggb = (__half*)nxt((size_t)NPAD * K1 * 2);   // 19.3 MB
  __half* h2   = (__half*)nxt((size_t)NPAD * NP2 * 2);  // 23.1 MB
  __half* w1t  = (__half*)nxt((size_t)LAYERS * NP1 * K1 * 2);
  __half* w2t  = (__half*)nxt((size_t)LAYERS * NP2 * NP1 * 2);
  float*  b1p  = (float*)nxt((size_t)LAYERS * NP1 * 4);
  float*  b2p  = (float*)nxt((size_t)LAYERS * NP2 * 4);
  float*  stat = (float*)nxt((size_t)LAYERS * 2 * EMB * 4);
  int*    deg  = (int*)nxt((size_t)N_NODES * 4);
  int*    rptr = (int*)nxt((size_t)(N_NODES + 1) * 4);
  int*    curs = (int*)nxt((size_t)N_NODES * 4);
  int*    ebuf = (int*)nxt((size_t)N_EDGES * 4);
  // total ~92 MB

  prep_kernel<<<2048, 256, 0, stream>>>(W1, W2, b1, b2, x, x_emb1, x_emb2,
                                        w1t, w2t, b1p, b2p, hbuf, deg, stat);

  count_kernel<<<(N_EDGES + 255) / 256, 256, 0, stream>>>(ei, deg);
  scan_kernel<<<1, 1024, 0, stream>>>(deg, rptr, curs);
  fill_kernel<<<(N_EDGES + 255) / 256, 256, 0, stream>>>(ei, ea, curs, ebuf);

  for (int l = 0; l < LAYERS; ++l) {
    if (l == 0) {
      aggregate_kernel<0><<<2048, 256, 0, stream>>>(
          hbuf, nullptr, nullptr, nullptr, rptr, ebuf,
          edge1 + (size_t)l * 6 * EMB, edge2 + (size_t)l * 3 * EMB, aggb);
    } else {
      aggregate_kernel<1><<<2048, 256, 0, stream>>>(
          h2, stat + (size_t)(l - 1) * 2 * EMB,
          gamma + (size_t)(l - 1) * EMB, beta + (size_t)(l - 1) * EMB,
          rptr, ebuf,
          edge1 + (size_t)l * 6 * EMB, edge2 + (size_t)l * 3 * EMB, aggb);
    }
    gemm_kernel<1, 0><<<dim3(NP1 / 128, NPAD / 128), 256, 0, stream>>>(
        aggb, K1, w1t + (size_t)l * NP1 * K1, K1, b1p + l * NP1, tbuf, NP1, K1, nullptr);
    gemm_kernel<0, 1><<<dim3(NP2 / 128, NPAD / 128), 256, 0, stream>>>(
        tbuf, NP1, w2t + (size_t)l * NP2 * NP1, NP1, b2p + l * NP2, h2, NP2, NP1,
        stat + l * 2 * EMB);
  }
  bn_kernel<<<1024, 256, 0, stream>>>(
      h2, stat + (size_t)(LAYERS - 1) * 2 * EMB,
      gamma + (size_t)(LAYERS - 1) * EMB, beta + (size_t)(LAYERS - 1) * EMB, out);
}

// Round 15
// 681.853 us; speedup vs baseline: 1.0704x; 1.0531x over previous
//
#include <hip/hip_runtime.h>
#include <hip/hip_fp16.h>

#define N_NODES 30000
#define N_EDGES 240000
#define EMB     300
#define NPAD    30080   // 235 * 128
#define K1      320     // padded EMB (gemm1 K, agg cols, fp16)
#define NP1     640     // padded 2*EMB (gemm1 out cols = gemm2 K)
#define NP2     384     // gemm2 padded col count / h2 fp16 row stride
#define HSH     304     // h row stride in fp16 elements
#define LAYERS  5

typedef _Float16 half8 __attribute__((ext_vector_type(8)));
typedef __attribute__((ext_vector_type(4))) float floatx4;
typedef float v2f __attribute__((ext_vector_type(2)));

// async 16B global->LDS (per-lane gptr, LDS dest = wave-uniform base + lane*16)
__device__ __forceinline__ void gload16(const void* g, void* l) {
  __builtin_amdgcn_global_load_lds(
      (const __attribute__((address_space(1))) unsigned int*)g,
      (__attribute__((address_space(3))) unsigned int*)l, 16, 0, 0);
}

__device__ __forceinline__ v2f h2f(__half2 h) {
  float2 f = __half22float2(h);
  v2f r; r.x = f.x; r.y = f.y; return r;
}

// ---------------- fused prep: zero deg/stat, convert weights, embed ----------------
__global__ __launch_bounds__(256)
void prep_kernel(const float* __restrict__ W1, const float* __restrict__ W2,
                 const float* __restrict__ b1, const float* __restrict__ b2,
                 const int* __restrict__ x, const float* __restrict__ emb1,
                 const float* __restrict__ emb2,
                 __half* __restrict__ w1t, __half* __restrict__ w2t,
                 float* __restrict__ b1p, float* __restrict__ b2p,
                 __half* __restrict__ h, int* __restrict__ deg,
                 float* __restrict__ stat) {
  const int Z0 = N_NODES;                       // deg zero
  const int Z1 = Z0 + LAYERS * 2 * EMB;         // stat zero
  const int R0 = Z1 + LAYERS * NP1 * K1;        // w1t
  const int R1 = R0 + LAYERS * NP2 * NP1;       // w2t
  const int R2 = R1 + LAYERS * NP1;             // b1p
  const int R3 = R2 + LAYERS * NP2;             // b2p
  const int R4 = R3 + N_NODES * HSH;            // embed
  for (int i = blockIdx.x * 256 + threadIdx.x; i < R4; i += gridDim.x * 256) {
    if (i < Z0) {
      deg[i] = 0;
    } else if (i < Z1) {
      stat[i - Z0] = 0.f;
    } else if (i < R0) {
      int idx = i - Z1;
      int l = idx / (NP1 * K1);
      int rem = idx % (NP1 * K1);
      int n = rem / K1, k = rem % K1;
      float v = (n < 2 * EMB && k < EMB)
                    ? W1[(size_t)l * EMB * 2 * EMB + (size_t)k * 2 * EMB + n] : 0.f;
      w1t[idx] = __float2half(v);
    } else if (i < R1) {
      int idx = i - R0;
      int l = idx / (NP2 * NP1);
      int rem = idx % (NP2 * NP1);
      int n = rem / NP1, k = rem % NP1;
      float v = (n < EMB && k < 2 * EMB)
                    ? W2[(size_t)l * 2 * EMB * EMB + (size_t)k * EMB + n] : 0.f;
      w2t[idx] = __float2half(v);
    } else if (i < R2) {
      int idx = i - R1;
      int l = idx / NP1, j = idx % NP1;
      b1p[idx] = (j < 2 * EMB) ? b1[l * 2 * EMB + j] : 0.f;
    } else if (i < R3) {
      int idx = i - R2;
      int l = idx / NP2, j = idx % NP2;
      b2p[idx] = (j < EMB) ? b2[l * EMB + j] : 0.f;
    } else {
      int j = i - R3;
      int node = j / HSH, c = j - node * HSH;
      if (c < EMB) {
        int t0 = x[node * 2], t1 = x[node * 2 + 1];
        h[(size_t)node * HSH + c] = __float2half(emb1[t0 * EMB + c] + emb2[t1 * EMB + c]);
      }
    }
  }
}

// ---------------- CSR build ----------------
__global__ void count_kernel(const int* __restrict__ ei, int* __restrict__ deg) {
  int e = blockIdx.x * 256 + threadIdx.x;
  if (e < N_EDGES) atomicAdd(&deg[ei[N_EDGES + e]], 1);
}

#define SCH 30   // 1024 * 30 = 30720 >= N_NODES
__global__ __launch_bounds__(1024)
void scan_kernel(const int* __restrict__ deg, int* __restrict__ row_ptr,
                 int* __restrict__ curs) {
  int tid = threadIdx.x;
  int base = tid * SCH;
  int loc[SCH];
  int s = 0;
#pragma unroll
  for (int j = 0; j < SCH; ++j) {
    int i = base + j;
    int v = (i < N_NODES) ? deg[i] : 0;
    loc[j] = s;          // exclusive prefix within chunk
    s += v;
  }
  int lane = tid & 63, wv = tid >> 6;
  int x = s;
#pragma unroll
  for (int o = 1; o < 64; o <<= 1) {
    int y = __shfl_up(x, o, 64);
    if (lane >= o) x += y;
  }
  __shared__ int wsum[16], woff[16];
  if (lane == 63) wsum[wv] = x;
  __syncthreads();
  if (tid == 0) {
    int acc = 0;
    for (int w = 0; w < 16; ++w) { woff[w] = acc; acc += wsum[w]; }
    row_ptr[N_NODES] = acc;
  }
  __syncthreads();
  int excl = woff[wv] + x - s;    // exclusive prefix of this thread's chunk
#pragma unroll
  for (int j = 0; j < SCH; ++j) {
    int i = base + j;
    if (i < N_NODES) { int val = excl + loc[j]; row_ptr[i] = val; curs[i] = val; }
  }
}

__global__ void fill_kernel(const int* __restrict__ ei, const int* __restrict__ ea,
                            int* __restrict__ cursor, int* __restrict__ ebuf) {
  int e = blockIdx.x * 256 + threadIdx.x;
  if (e >= N_EDGES) return;
  int d = ei[N_EDGES + e];
  int pos = atomicAdd(&cursor[d], 1);
  ebuf[pos] = ei[e] * 32 + (ea[2 * e] * 3 + ea[2 * e + 1]);  // src*32 + combo
}

// ---------------- aggregation: persistent blocks, fused BN+ReLU, 4-edge batch ----------------
// R10-EXACT body (measured 45.1-45.2us, VGPR 36). Locked.
template<int BN>
__global__ __launch_bounds__(256)
void aggregate_kernel(const __half* __restrict__ h,   // BN ? h2 : hbuf
                      const float* __restrict__ stats,  // prev layer (BN only)
                      const float* __restrict__ gamma,  // prev layer (BN only)
                      const float* __restrict__ beta,   // prev layer (BN only)
                      const int* __restrict__ row_ptr,
                      const int* __restrict__ ebuf,
                      const float* __restrict__ e1,   // [6,300] this layer
                      const float* __restrict__ e2,   // [3,300] this layer
                      __half* __restrict__ agg) {
  const int STR = BN ? NP2 : HSH;   // fp16 row stride of gather source
  __shared__ __half2 combo[18][150];   // 10.8 KB
  int tid = threadIdx.x;
  for (int idx = tid; idx < 18 * 150; idx += 256) {
    int t = idx / 150, p = idx % 150;
    int a0 = t / 3, a1 = t % 3;
    combo[t][p] = __floats2half2_rn(e1[a0 * EMB + 2 * p]     + e2[a1 * EMB + 2 * p],
                                    e1[a0 * EMB + 2 * p + 1] + e2[a1 * EMB + 2 * p + 1]);
  }
  __syncthreads();
  int wave = tid >> 6, lane = tid & 63;
  int p2 = lane + 128;
  bool has2 = (p2 < 150);

  // per-thread BN scale/shift for the 3 owned half2 column pairs
  v2f sc[3], sh[3];
  if (BN) {
    const float invN = 1.0f / (float)N_NODES;
    int cols[3] = {2 * lane, 2 * (lane + 64), 2 * p2};
#pragma unroll
    for (int k = 0; k < 3; ++k) {
      if (k == 2 && !has2) { sc[2].x = sc[2].y = 1.f; sh[2].x = sh[2].y = 0.f; break; }
      int c = cols[k];
      float m0 = stats[c] * invN, m1 = stats[c + 1] * invN;
      float va = stats[EMB + c] * invN - m0 * m0;
      float vb = stats[EMB + c + 1] * invN - m1 * m1;
      sc[k].x = gamma[c] * rsqrtf(va + 1e-5f);      sh[k].x = beta[c] - m0 * sc[k].x;
      sc[k].y = gamma[c + 1] * rsqrtf(vb + 1e-5f);  sh[k].y = beta[c + 1] - m1 * sc[k].y;
    }
  }
  // gathered-value transform: BN ? relu(x*sc+sh) : x
  auto xf = [&](__half2 x, int k) -> v2f {
    v2f f = h2f(x);
    if (BN) {
      f = f * sc[k] + sh[k];
      f.x = fmaxf(f.x, 0.f); f.y = fmaxf(f.y, 0.f);
    }
    return f;
  };

  for (int node = blockIdx.x * 4 + wave; node < NPAD; node += gridDim.x * 4) {
    float a0x = 0.f, a0y = 0.f, a1x = 0.f, a1y = 0.f, a2x = 0.f, a2y = 0.f;
    float b0x = 0.f, b0y = 0.f, b1x = 0.f, b1y = 0.f, b2x = 0.f, b2y = 0.f;
    if (node < N_NODES) {
      int ebeg = row_ptr[node], eend = row_ptr[node + 1];
      int e = ebeg;
      // ---- 4-edge unrolled main loop: batch all loads, then accumulate ----
      for (; e + 4 <= eend; e += 4) {
        int v0 = ebuf[e], v1 = ebuf[e + 1], v2 = ebuf[e + 2], v3 = ebuf[e + 3];
        const __half2* hp0 = (const __half2*)(h + (size_t)(v0 >> 5) * STR);
        const __half2* hp1 = (const __half2*)(h + (size_t)(v1 >> 5) * STR);
        const __half2* hp2 = (const __half2*)(h + (size_t)(v2 >> 5) * STR);
        const __half2* hp3 = (const __half2*)(h + (size_t)(v3 >> 5) * STR);
        int t0 = v0 & 31, t1 = v1 & 31, t2 = v2 & 31, t3 = v3 & 31;
        __half2 x00 = hp0[lane], x01 = hp0[lane + 64];
        __half2 x10 = hp1[lane], x11 = hp1[lane + 64];
        __half2 x20 = hp2[lane], x21 = hp2[lane + 64];
        __half2 x30 = hp3[lane], x31 = hp3[lane + 64];
        __half2 x02, x12, x22, x32;
        if (has2) { x02 = hp0[p2]; x12 = hp1[p2]; x22 = hp2[p2]; x32 = hp3[p2]; }
        __half2 c00 = combo[t0][lane], c01 = combo[t0][lane + 64];
        __half2 c10 = combo[t1][lane], c11 = combo[t1][lane + 64];
        __half2 c20 = combo[t2][lane], c21 = combo[t2][lane + 64];
        __half2 c30 = combo[t3][lane], c31 = combo[t3][lane + 64];
        v2f g; float2 f;
        g = xf(x00, 0); a0x += g.x; a0y += g.y;
        f = __half22float2(c00); a0x += f.x; a0y += f.y;
        g = xf(x01, 1); a1x += g.x; a1y += g.y;
        f = __half22float2(c01); a1x += f.x; a1y += f.y;
        g = xf(x10, 0); b0x += g.x; b0y += g.y;
        f = __half22float2(c10); b0x += f.x; b0y += f.y;
        g = xf(x11, 1); b1x += g.x; b1y += g.y;
        f = __half22float2(c11); b1x += f.x; b1y += f.y;
        g = xf(x20, 0); a0x += g.x; a0y += g.y;
        f = __half22float2(c20); a0x += f.x; a0y += f.y;
        g = xf(x21, 1); a1x += g.x; a1y += g.y;
        f = __half22float2(c21); a1x += f.x; a1y += f.y;
        g = xf(x30, 0); b0x += g.x; b0y += g.y;
        f = __half22float2(c30); b0x += f.x; b0y += f.y;
        g = xf(x31, 1); b1x += g.x; b1y += g.y;
        f = __half22float2(c31); b1x += f.x; b1y += f.y;
        if (has2) {
          g = xf(x02, 2); a2x += g.x; a2y += g.y;
          f = __half22float2(combo[t0][p2]); a2x += f.x; a2y += f.y;
          g = xf(x12, 2); b2x += g.x; b2y += g.y;
          f = __half22float2(combo[t1][p2]); b2x += f.x; b2y += f.y;
          g = xf(x22, 2); a2x += g.x; a2y += g.y;
          f = __half22float2(combo[t2][p2]); a2x += f.x; a2y += f.y;
          g = xf(x32, 2); b2x += g.x; b2y += g.y;
          f = __half22float2(combo[t3][p2]); b2x += f.x; b2y += f.y;
        }
      }
      // ---- 2-edge pairs ----
      for (; e + 2 <= eend; e += 2) {
        int v0 = ebuf[e], v1 = ebuf[e + 1];
        int s0 = v0 >> 5, t0 = v0 & 31;
        int s1 = v1 >> 5, t1 = v1 & 31;
        const __half2* hp0 = (const __half2*)(h + (size_t)s0 * STR);
        const __half2* hp1 = (const __half2*)(h + (size_t)s1 * STR);
        v2f g; float2 f;
        g = xf(hp0[lane], 0);      a0x += g.x; a0y += g.y;
        f = __half22float2(combo[t0][lane]); a0x += f.x; a0y += f.y;
        g = xf(hp0[lane + 64], 1); a1x += g.x; a1y += g.y;
        f = __half22float2(combo[t0][lane + 64]); a1x += f.x; a1y += f.y;
        g = xf(hp1[lane], 0);      b0x += g.x; b0y += g.y;
        f = __half22float2(combo[t1][lane]); b0x += f.x; b0y += f.y;
        g = xf(hp1[lane + 64], 1); b1x += g.x; b1y += g.y;
        f = __half22float2(combo[t1][lane + 64]); b1x += f.x; b1y += f.y;
        if (has2) {
          g = xf(hp0[p2], 2); a2x += g.x; a2y += g.y;
          f = __half22float2(combo[t0][p2]); a2x += f.x; a2y += f.y;
          g = xf(hp1[p2], 2); b2x += g.x; b2y += g.y;
          f = __half22float2(combo[t1][p2]); b2x += f.x; b2y += f.y;
        }
      }
      // ---- tail edge (if odd count) + self loop ----
      for (; e <= eend; ++e) {
        int s, t;
        if (e < eend) { int v = ebuf[e]; s = v >> 5; t = v & 31; }
        else          { s = node;        t = 4 * 3 + 0; }
        const __half2* hp = (const __half2*)(h + (size_t)s * STR);
        v2f g; float2 f;
        g = xf(hp[lane], 0);      a0x += g.x; a0y += g.y;
        f = __half22float2(combo[t][lane]); a0x += f.x; a0y += f.y;
        g = xf(hp[lane + 64], 1); a1x += g.x; a1y += g.y;
        f = __half22float2(combo[t][lane + 64]); a1x += f.x; a1y += f.y;
        if (has2) {
          g = xf(hp[p2], 2); a2x += g.x; a2y += g.y;
          f = __half22float2(combo[t][p2]); a2x += f.x; a2y += f.y;
        }
      }
    }
    a0x += b0x; a0y += b0y; a1x += b1x; a1y += b1y; a2x += b2x; a2y += b2y;
    __half2* op = (__half2*)(agg + (size_t)node * K1);
    op[lane]      = __floats2half2_rn(a0x, a0y);
    op[lane + 64] = __floats2half2_rn(a1x, a1y);
    if (p2 < 160) op[p2] = has2 ? __floats2half2_rn(a2x, a2y)
                                : __floats2half2_rn(0.f, 0.f);   // zero K-pad cols
  }
}

// ---------------- fp16 MFMA GEMM: C = act(A @ B^T + bias) ----------------
// R15: R10's lb(256,3) base (716.1us best) + XCD-chunked bijective swizzle
// (T1/m204) as the ONLY change. HW assigns XCD = blockIdx % 8, so with
// x-fastest dispatch the gx col-blocks sharing one A row-panel land on gx
// DIFFERENT per-XCD L2s (A re-fetched gx times from L3). The chunked remap
// gives each XCD a contiguous logical range -> those col-blocks co-locate.
// Remap verified bijective for nwg=1175 (7*147+146) and 705 (89+7*88).
template<int RELU, int STATS>
__global__ __launch_bounds__(256, 3)
void gemm_kernel(const __half* __restrict__ A, int lda,
                 const __half* __restrict__ Bt, int ldb,
                 const float* __restrict__ bias,
                 __half* __restrict__ C, int ldc, int K, int gx,
                 float* __restrict__ stats) {
  __shared__ _Float16 As[2][128 * 32];   // double-buffered, 32 KB A+B
  __shared__ _Float16 Bs[2][128 * 32];
  __shared__ float cs[128], cq[128];
  int tid = threadIdx.x;
  int wave = tid >> 6, lane = tid & 63;
  int wm = wave >> 1, wn = wave & 1;
  // bijective XCD-chunked remap (m204)
  int nwg = gridDim.x;
  int q = nwg >> 3, r = nwg & 7;
  int xcd = blockIdx.x & 7, sub = blockIdx.x >> 3;
  int wgid = (xcd < r ? xcd * (q + 1) : r * (q + 1) + (xcd - r) * q) + sub;
  int cb = wgid % gx;              // col-tile index (fastest within chunk)
  int col0 = cb * 128;
  int row0 = (wgid / gx) * 128;
  int sr = tid >> 2, sc = (tid & 3) * 8;           // staging row / fp16 col chunk
  const __half* ga0 = A + (size_t)(row0 + sr) * lda + sc;
  const __half* ga1 = A + (size_t)(row0 + 64 + sr) * lda + sc;
  const __half* gb0 = Bt + (size_t)(col0 + sr) * ldb + sc;
  const __half* gb1 = Bt + (size_t)(col0 + 64 + sr) * ldb + sc;
  int soff = sr * 32 + sc;                          // lane-linear: tid*16 bytes
  int aoff = (wm * 64 + (lane & 15)) * 32 + (lane >> 4) * 8;
  int boff = (wn * 64 + (lane & 15)) * 32 + (lane >> 4) * 8;

  if (STATS && tid < 128) { cs[tid] = 0.f; cq[tid] = 0.f; }

  floatx4 zero4 = {0.f, 0.f, 0.f, 0.f};
  floatx4 acc[4][4];
#pragma unroll
  for (int i = 0; i < 4; ++i)
#pragma unroll
    for (int j = 0; j < 4; ++j) acc[i][j] = zero4;

  // prologue: stage tile 0 into buffer 0
  gload16(ga0, &As[0][soff]);
  gload16(ga1, &As[0][soff + 2048]);
  gload16(gb0, &Bs[0][soff]);
  gload16(gb1, &Bs[0][soff + 2048]);
  __syncthreads();   // vmcnt(0) drain + barrier: tile 0 resident

  int nT = K >> 5;
  int cur = 0;
  for (int t = 0; t < nT; ++t) {
    if (t + 1 < nT) {            // issue next-tile loads BEFORE compute
      int kc = (t + 1) << 5;
      int nb = cur ^ 1;
      gload16(ga0 + kc, &As[nb][soff]);
      gload16(ga1 + kc, &As[nb][soff + 2048]);
      gload16(gb0 + kc, &Bs[nb][soff]);
      gload16(gb1 + kc, &Bs[nb][soff + 2048]);
    }
    half8 af[4], bfr[4];
#pragma unroll
    for (int mi = 0; mi < 4; ++mi)
      af[mi] = *(const half8*)&As[cur][aoff + mi * 512];
#pragma unroll
    for (int ni = 0; ni < 4; ++ni)
      bfr[ni] = *(const half8*)&Bs[cur][boff + ni * 512];
#pragma unroll
    for (int mi = 0; mi < 4; ++mi)
#pragma unroll
      for (int ni = 0; ni < 4; ++ni)
        acc[mi][ni] = __builtin_amdgcn_mfma_f32_16x16x32_f16(af[mi], bfr[ni], acc[mi][ni], 0, 0, 0);
    __syncthreads();   // one barrier/K-step: next tile ready + reads of cur done
    cur ^= 1;
  }

  // epilogue: C/D layout col=lane&15, row=quad*4+reg
  float ls[4] = {0.f, 0.f, 0.f, 0.f}, lq[4] = {0.f, 0.f, 0.f, 0.f};
#pragma unroll
  for (int mi = 0; mi < 4; ++mi) {
#pragma unroll
    for (int ni = 0; ni < 4; ++ni) {
      int col = col0 + wn * 64 + ni * 16 + (lane & 15);
      float bv = bias[col];
#pragma unroll
      for (int r2 = 0; r2 < 4; ++r2) {
        int row = row0 + wm * 64 + mi * 16 + (lane >> 4) * 4 + r2;
        float v = acc[mi][ni][r2] + bv;
        if (RELU) v = fmaxf(v, 0.f);
        C[(size_t)row * ldc + col] = __float2half(v);
        if (STATS && row < N_NODES) { ls[ni] += v; lq[ni] += v * v; }
      }
    }
  }
  if (STATS) {
#pragma unroll
    for (int ni = 0; ni < 4; ++ni) {
      int ci = wn * 64 + ni * 16 + (lane & 15);
      atomicAdd(&cs[ci], ls[ni]);
      atomicAdd(&cq[ci], lq[ni]);
    }
    __syncthreads();
    int col = cb * 128 + tid;
    if (tid < 128 && col < EMB) {
      atomicAdd(&stats[col], cs[tid]);
      atomicAdd(&stats[EMB + col], cq[tid]);
    }
  }
}

// ---------------- batchnorm apply, final layer only: h2 -> fp32 out ----------------
__global__ __launch_bounds__(256)
void bn_kernel(const __half* __restrict__ h2, const float* __restrict__ stats,
               const float* __restrict__ gamma, const float* __restrict__ beta,
               float* __restrict__ fout) {
  const float invN = 1.0f / (float)N_NODES;
  const int total = N_NODES * 150;
  for (int i = blockIdx.x * 256 + threadIdx.x; i < total; i += gridDim.x * 256) {
    int node = i / 150;
    int c = (i - node * 150) * 2;
    float m0 = stats[c] * invN,      m1 = stats[c + 1] * invN;
    float v0 = stats[EMB + c] * invN - m0 * m0;
    float v1 = stats[EMB + c + 1] * invN - m1 * m1;
    float s0 = gamma[c] * rsqrtf(v0 + 1e-5f);
    float s1 = gamma[c + 1] * rsqrtf(v1 + 1e-5f);
    float t0 = beta[c] - m0 * s0, t1 = beta[c + 1] - m1 * s1;
    float2 u = __half22float2(*(const __half2*)&h2[(size_t)node * NP2 + c]);
    fout[(size_t)node * EMB + c]     = u.x * s0 + t0;
    fout[(size_t)node * EMB + c + 1] = u.y * s1 + t1;
  }
}

extern "C" void kernel_launch(void* const* d_in, const int* in_sizes, int n_in,
                              void* d_out, int out_size, void* d_ws, size_t ws_size,
                              hipStream_t stream) {
  const int*   x      = (const int*)d_in[0];
  const int*   ei     = (const int*)d_in[1];
  const int*   ea     = (const int*)d_in[2];
  const float* x_emb1 = (const float*)d_in[3];
  const float* x_emb2 = (const float*)d_in[4];
  const float* edge1  = (const float*)d_in[5];
  const float* edge2  = (const float*)d_in[6];
  const float* W1     = (const float*)d_in[7];
  const float* b1     = (const float*)d_in[8];
  const float* W2     = (const float*)d_in[9];
  const float* b2     = (const float*)d_in[10];
  const float* gamma  = (const float*)d_in[11];
  const float* beta   = (const float*)d_in[12];
  float* out = (float*)d_out;

  char* ws = (char*)d_ws;
  size_t off = 0;
  auto nxt = [&](size_t bytes) {
    void* p = ws + off;
    off += (bytes + 255) & ~(size_t)255;
    return p;
  };
  // Aliasing: h2 is READ by the next layer's aggregate (while aggb is
  // written), so h2 must NOT alias aggb. Timeline-checked layout:
  //   region R: hbuf (read only by layer-0 aggregate) aliases tbuf (first
  //             written at layer-0 gemm1, after hbuf's last read).
  //   aggb, h2: separate.
  size_t tbuf_bytes = (size_t)NPAD * NP1 * 2;        // 38.5 MB
  size_t hbuf_bytes = (size_t)N_NODES * HSH * 2;     // 18.2 MB
  char* R = (char*)nxt(tbuf_bytes > hbuf_bytes ? tbuf_bytes : hbuf_bytes);
  __half* hbuf = (__half*)R;
  __half* tbuf = (__half*)R;
  __half* aggb = (__half*)nxt((size_t)NPAD * K1 * 2);   // 19.3 MB
  __half* h2   = (__half*)nxt((size_t)NPAD * NP2 * 2);  // 23.1 MB
  __half* w1t  = (__half*)nxt((size_t)LAYERS * NP1 * K1 * 2);
  __half* w2t  = (__half*)nxt((size_t)LAYERS * NP2 * NP1 * 2);
  float*  b1p  = (float*)nxt((size_t)LAYERS * NP1 * 4);
  float*  b2p  = (float*)nxt((size_t)LAYERS * NP2 * 4);
  float*  stat = (float*)nxt((size_t)LAYERS * 2 * EMB * 4);
  int*    deg  = (int*)nxt((size_t)N_NODES * 4);
  int*    rptr = (int*)nxt((size_t)(N_NODES + 1) * 4);
  int*    curs = (int*)nxt((size_t)N_NODES * 4);
  int*    ebuf = (int*)nxt((size_t)N_EDGES * 4);
  // total ~92 MB

  prep_kernel<<<2048, 256, 0, stream>>>(W1, W2, b1, b2, x, x_emb1, x_emb2,
                                        w1t, w2t, b1p, b2p, hbuf, deg, stat);

  count_kernel<<<(N_EDGES + 255) / 256, 256, 0, stream>>>(ei, deg);
  scan_kernel<<<1, 1024, 0, stream>>>(deg, rptr, curs);
  fill_kernel<<<(N_EDGES + 255) / 256, 256, 0, stream>>>(ei, ea, curs, ebuf);

  const int nwg1 = (NP1 / 128) * (NPAD / 128);   // 5 * 235 = 1175
  const int nwg2 = (NP2 / 128) * (NPAD / 128);   // 3 * 235 = 705

  for (int l = 0; l < LAYERS; ++l) {
    if (l == 0) {
      aggregate_kernel<0><<<2048, 256, 0, stream>>>(
          hbuf, nullptr, nullptr, nullptr, rptr, ebuf,
          edge1 + (size_t)l * 6 * EMB, edge2 + (size_t)l * 3 * EMB, aggb);
    } else {
      aggregate_kernel<1><<<2048, 256, 0, stream>>>(
          h2, stat + (size_t)(l - 1) * 2 * EMB,
          gamma + (size_t)(l - 1) * EMB, beta + (size_t)(l - 1) * EMB,
          rptr, ebuf,
          edge1 + (size_t)l * 6 * EMB, edge2 + (size_t)l * 3 * EMB, aggb);
    }
    gemm_kernel<1, 0><<<nwg1, 256, 0, stream>>>(
        aggb, K1, w1t + (size_t)l * NP1 * K1, K1, b1p + l * NP1, tbuf, NP1, K1,
        NP1 / 128, nullptr);
    gemm_kernel<0, 1><<<nwg2, 256, 0, stream>>>(
        tbuf, NP1, w2t + (size_t)l * NP2 * NP1, NP1, b2p + l * NP2, h2, NP2, NP1,
        NP2 / 128, stat + l * 2 * EMB);
  }
  bn_kernel<<<1024, 256, 0, stream>>>(
      h2, stat + (size_t)(LAYERS - 1) * 2 * EMB,
      gamma + (size_t)(LAYERS - 1) * EMB, beta + (size_t)(LAYERS - 1) * EMB, out);
}